// Round 1
// baseline (397.344 us; speedup 1.0000x reference)
//
#include <hip/hip_runtime.h>
#include <math.h>

// ---------------------------------------------------------------------------
// Branch kernel: per (bn) block computes one multi-scale branch:
//   t1 = relu(conv1d(x, w1, b1))          (64 x 200, in LDS)
//   o  = relu(conv1d(t1, w2, b2))         (128 x 200, never materialized)
//   pooled[bn][br*1280 + co*10 + bin] = mean over 20 l of o[co][l]
// Mask is a per-row 0/1 scalar (mask-convs are identity on constant rows).
// ---------------------------------------------------------------------------
template<int K>
__global__ __launch_bounds__(256) void branch_kernel(
    const float* __restrict__ x,      // (512, 200)
    const float* __restrict__ xmask,  // (512,)
    const float* __restrict__ w1,     // (64, 1, K)
    const float* __restrict__ b1,     // (64,)
    const float* __restrict__ w2,     // (128, 64, K)
    const float* __restrict__ b2,     // (128,)
    float* __restrict__ pooled,       // (512, 3840)
    int br)
{
    constexpr int PAD = (K - 1) / 2;
    const int bn = blockIdx.x;
    const int t  = threadIdx.x;
    float* pout = pooled + bn * 3840 + br * 1280;

    if (xmask[bn] == 0.0f) {
        for (int i = t; i < 1280; i += 256) pout[i] = 0.0f;
        return;
    }

    __shared__ float xs[208];       // x row, offset +3, zero halo (max pad 3)
    __shared__ float t1[64][208];   // conv1 output, offset +3, zero halo

    if (t < 208) xs[t] = 0.0f;
    if (t < 384) {                  // zero t1 halos: per ci positions 0..2, 203..205
        int ci = t / 6, k = t % 6;
        int pos = (k < 3) ? k : (200 + k);
        t1[ci][pos] = 0.0f;
    }
    __syncthreads();
    if (t < 200) xs[3 + t] = x[bn * 200 + t];
    __syncthreads();

    // conv1: 64 ch x 200 l
    for (int idx = t; idx < 12800; idx += 256) {
        int ci = idx / 200;
        int l  = idx - ci * 200;
        float a = b1[ci];
        #pragma unroll
        for (int j = 0; j < K; ++j)
            a = fmaf(w1[ci * K + j], xs[3 + l + j - PAD], a);
        t1[ci][3 + l] = fmaxf(a, 0.0f);
    }
    __syncthreads();

    // conv2 + relu + 20-wide mean pool.
    // thread -> (co = t>>1) output channel, (p = t&1) bin parity.
    // acc[100] = 5 bins x 20 positions, fully static-indexed (all loops unrolled).
    // All t1 reads are wave-uniform addresses -> LDS broadcast, conflict-free.
    const int co = t >> 1;
    const int p  = t & 1;
    float acc[100];
    #pragma unroll
    for (int i = 0; i < 100; ++i) acc[i] = 0.0f;

    for (int ci = 0; ci < 64; ++ci) {
        float w[K];
        #pragma unroll
        for (int j = 0; j < K; ++j) w[j] = w2[(co * 64 + ci) * K + j];
        #pragma unroll
        for (int b = 0; b < 5; ++b) {
            const int l0 = (2 * b + p) * 20;
            float tr[20 + 2 * PAD];
            #pragma unroll
            for (int i = 0; i < 20 + 2 * PAD; ++i)
                tr[i] = t1[ci][3 - PAD + l0 + i];
            #pragma unroll
            for (int l = 0; l < 20; ++l) {
                #pragma unroll
                for (int j = 0; j < K; ++j)
                    acc[b * 20 + l] = fmaf(w[j], tr[l + j], acc[b * 20 + l]);
            }
        }
    }
    const float bb = b2[co];
    #pragma unroll
    for (int b = 0; b < 5; ++b) {
        float ps = 0.0f;
        #pragma unroll
        for (int l = 0; l < 20; ++l)
            ps += fmaxf(acc[b * 20 + l] + bb, 0.0f);
        pout[co * 10 + (2 * b + p)] = ps * 0.05f;   // mean over 20
    }
}

// ---------------------------------------------------------------------------
// xfc: xfeat(512,32) = (pooled @ w_xfc.T + b_xfc) * valid
// ---------------------------------------------------------------------------
__global__ __launch_bounds__(256) void xfc_kernel(
    const float* __restrict__ pooled,   // (512, 3840)
    const float* __restrict__ w_xfc,    // (32, 3840)
    const float* __restrict__ b_xfc,    // (32,)
    const float* __restrict__ xmask,    // (512,)
    float* __restrict__ xfeat)          // (512, 32)
{
    const int bn = blockIdx.x;
    const int t  = threadIdx.x;
    __shared__ float prow[3840];
    const float* pr = pooled + bn * 3840;
    for (int i = t; i < 3840; i += 256) prow[i] = pr[i];
    __syncthreads();

    const int o = t >> 3, part = t & 7;   // 8 threads per output
    const float* wr = w_xfc + o * 3840;
    float a = 0.0f;
    for (int i = part; i < 3840; i += 8)
        a = fmaf(prow[i], wr[i], a);
    a += __shfl_xor(a, 1);
    a += __shfl_xor(a, 2);
    a += __shfl_xor(a, 4);
    if (part == 0) xfeat[bn * 32 + o] = (a + b_xfc[o]) * xmask[bn];
}

// ---------------------------------------------------------------------------
// Tail: elements processor + fuse + 4-head attention + pool + regressor.
// One block per batch b (32 blocks).
// ---------------------------------------------------------------------------
__global__ __launch_bounds__(256) void tail_kernel(
    const float* __restrict__ xfeat,      // (512, 32)
    const float* __restrict__ elem_info,  // (32, 16, 7)
    const float* __restrict__ emaskp,     // (32, 16)
    const float* __restrict__ w_float, const float* __restrict__ b_float,
    const float* __restrict__ atom_emb, const float* __restrict__ type_emb,
    const float* __restrict__ w_fuse,  const float* __restrict__ b_fuse,
    const float* __restrict__ in_w,    const float* __restrict__ in_b,
    const float* __restrict__ out_w,   const float* __restrict__ out_b,
    const float* __restrict__ w_fc1,   const float* __restrict__ b_fc1,
    const float* __restrict__ w_fc2,   const float* __restrict__ b_fc2,
    float* __restrict__ out)              // (32,)
{
    const int b = blockIdx.x;
    const int t = threadIdx.x;

    __shared__ float fu[16][60];      // [xfeat(32) | ff(16) | ez(8) | ety(4)]
    __shared__ float fused[16][64];
    __shared__ float qkvs[16][192];   // q | k | v
    __shared__ float sc[4][16][16];
    __shared__ float ao[16][64];
    __shared__ float aoo[16][64];
    __shared__ float p2s[64];
    __shared__ float hs[64];
    __shared__ float em[16];

    if (t < 16) em[t] = emaskp[b * 16 + t];
    for (int d = t; d < 512; d += 256) {            // xfeat -> fu[:, 0:32]
        int n = d >> 5, o = d & 31;
        fu[n][o] = xfeat[(b * 16 + n) * 32 + o];
    }
    __syncthreads();

    // ---- element features: 16 threads per n ----
    {
        int n = t >> 4, slot = t & 15;
        float m  = em[n];
        float vE = (m >= 0.5f) ? 1.0f : 0.0f;
        const float* ei = elem_info + (b * 16 + n) * 7;
        float a = b_float[slot];
        #pragma unroll
        for (int i = 0; i < 5; ++i)
            a = fmaf(ei[i] * m, w_float[slot * 5 + i], a);
        fu[n][32 + slot] = fmaxf(a, 0.0f) * vE * m;

        int an = (int)(ei[5] * m);
        int et = (int)(ei[6] * m);
        float take = (vE != 0.0f && an >= 1 && an <= 94) ? 1.0f : 0.0f;
        int anc = an < 0 ? 0 : (an > 94 ? 94 : an);
        int etc = et < 0 ? 0 : (et > 5 ? 5 : et);
        if (slot < 8)
            fu[n][48 + slot] = atom_emb[anc * 8 + slot] * take * m;
        else if (slot < 12)
            fu[n][56 + (slot - 8)] = type_emb[etc * 4 + (slot - 8)] * take * m;
    }
    __syncthreads();

    // ---- fuse: (16 x 60) @ (64 x 60)^T ----
    for (int d = t; d < 1024; d += 256) {
        int n = d >> 6, o = d & 63;
        float a = b_fuse[o];
        const float* wr = w_fuse + o * 60;
        #pragma unroll
        for (int i = 0; i < 60; ++i) a = fmaf(fu[n][i], wr[i], a);
        fused[n][o] = a * em[n];
    }
    __syncthreads();

    // ---- qkv projection ----
    for (int d = t; d < 3072; d += 256) {
        int n = d / 192, rr = d - n * 192;
        float a = in_b[rr];
        const float* wr = in_w + rr * 64;
        #pragma unroll
        for (int i = 0; i < 64; ++i) a = fmaf(fused[n][i], wr[i], a);
        qkvs[n][rr] = a;
    }
    __syncthreads();

    // ---- scores (h,i,j) ----
    for (int d = t; d < 1024; d += 256) {
        int h = d >> 8, i = (d >> 4) & 15, j = d & 15;
        float a = 0.0f;
        #pragma unroll
        for (int dd = 0; dd < 16; ++dd)
            a = fmaf(qkvs[i][h * 16 + dd], qkvs[j][64 + h * 16 + dd], a);
        a *= 0.25f;                                 // 1/sqrt(16)
        if (em[j] < 0.5f) a = -1e30f;
        sc[h][i][j] = a;
    }
    __syncthreads();

    // ---- softmax over j, one thread per (h,i) row ----
    if (t < 64) {
        int h = t >> 4, i = t & 15;
        float mx = -3.4e38f;
        #pragma unroll
        for (int j = 0; j < 16; ++j) mx = fmaxf(mx, sc[h][i][j]);
        float e[16];
        float s = 0.0f;
        #pragma unroll
        for (int j = 0; j < 16; ++j) { e[j] = expf(sc[h][i][j] - mx); s += e[j]; }
        float inv = 1.0f / s;
        #pragma unroll
        for (int j = 0; j < 16; ++j) sc[h][i][j] = e[j] * inv;
    }
    __syncthreads();

    // ---- attn @ V ----
    for (int d = t; d < 1024; d += 256) {
        int n = d >> 6, e = d & 63, h = e >> 4;
        float a = 0.0f;
        #pragma unroll
        for (int j = 0; j < 16; ++j)
            a = fmaf(sc[h][n][j], qkvs[j][128 + e], a);
        ao[n][e] = a;
    }
    __syncthreads();

    // ---- output projection ----
    for (int d = t; d < 1024; d += 256) {
        int n = d >> 6, o = d & 63;
        float a = out_b[o];
        const float* wr = out_w + o * 64;
        #pragma unroll
        for (int i = 0; i < 64; ++i) a = fmaf(ao[n][i], wr[i], a);
        aoo[n][o] = a * em[n];
    }
    __syncthreads();

    // ---- masked mean pool ----
    if (t < 64) {
        float s = 0.0f, ms = 0.0f;
        #pragma unroll
        for (int n = 0; n < 16; ++n) { s += aoo[n][t]; ms += em[n]; }
        p2s[t] = s / (ms + 1e-8f);
    }
    __syncthreads();

    // ---- fc1 + relu ----
    if (t < 64) {
        float a = b_fc1[t];
        const float* wr = w_fc1 + t * 64;
        #pragma unroll
        for (int i = 0; i < 64; ++i) a = fmaf(p2s[i], wr[i], a);
        hs[t] = fmaxf(a, 0.0f);
    }
    __syncthreads();

    // ---- fc2 (wave-0 reduce) ----
    if (t < 64) {
        float v = hs[t] * w_fc2[t];
        #pragma unroll
        for (int d2 = 32; d2 >= 1; d2 >>= 1) v += __shfl_xor(v, d2);
        if (t == 0) out[b] = v + b_fc2[0];
    }
}

extern "C" void kernel_launch(void* const* d_in, const int* in_sizes, int n_in,
                              void* d_out, int out_size, void* d_ws, size_t ws_size,
                              hipStream_t stream)
{
    (void)in_sizes; (void)n_in; (void)out_size; (void)ws_size;
    const float* x     = (const float*)d_in[0];
    const float* xmask = (const float*)d_in[1];
    const float* einfo = (const float*)d_in[2];
    const float* emask = (const float*)d_in[3];

    float* pooled = (float*)d_ws;            // 512*3840 f32 = 7.86 MB
    float* xfeat  = pooled + 512 * 3840;     // 512*32 f32

    branch_kernel<3><<<512, 256, 0, stream>>>(x, xmask,
        (const float*)d_in[4],  (const float*)d_in[5],
        (const float*)d_in[6],  (const float*)d_in[7],  pooled, 0);
    branch_kernel<5><<<512, 256, 0, stream>>>(x, xmask,
        (const float*)d_in[8],  (const float*)d_in[9],
        (const float*)d_in[10], (const float*)d_in[11], pooled, 1);
    branch_kernel<7><<<512, 256, 0, stream>>>(x, xmask,
        (const float*)d_in[12], (const float*)d_in[13],
        (const float*)d_in[14], (const float*)d_in[15], pooled, 2);

    xfc_kernel<<<512, 256, 0, stream>>>(pooled,
        (const float*)d_in[16], (const float*)d_in[17], xmask, xfeat);

    tail_kernel<<<32, 256, 0, stream>>>(xfeat, einfo, emask,
        (const float*)d_in[18], (const float*)d_in[19],
        (const float*)d_in[20], (const float*)d_in[21],
        (const float*)d_in[22], (const float*)d_in[23],
        (const float*)d_in[24], (const float*)d_in[25],
        (const float*)d_in[26], (const float*)d_in[27],
        (const float*)d_in[28], (const float*)d_in[29],
        (const float*)d_in[30], (const float*)d_in[31],
        (float*)d_out);
}

// Round 2
// 332.048 us; speedup vs baseline: 1.1966x; 1.1966x over previous
//
#include <hip/hip_runtime.h>
#include <math.h>

typedef float f32x4 __attribute__((ext_vector_type(4)));
typedef short short8 __attribute__((ext_vector_type(8)));

__device__ __forceinline__ short bf16r(float f) {
    union { float f; unsigned u; } x; x.f = f;
    unsigned u = x.u + 0x7fffu + ((x.u >> 16) & 1u);
    return (short)(u >> 16);
}

// ---------------------------------------------------------------------------
// pack_kernel: repack w2 (co,ci,j) fp32 -> B-fragment-ordered bf16 so that an
// MFMA B-frag (16x16x32: lane holds B[8*(lane>>4)+i][lane&15]) is one
// coalesced 16B/lane load: wpack[(((c*K+j)*2+kb)*64+lane)*8 + i]
//   element = w2[co = c*16+(lane&15)][ci = kb*32+8*((lane>>4)&3)+i][j]
// ---------------------------------------------------------------------------
template<int K>
__device__ __forceinline__ void pack_branch(const float* __restrict__ w2,
                                            short* __restrict__ wpack, int u) {
    int lane = u & 63;
    int kb   = (u >> 6) & 1;
    int rem  = u >> 7;          // c*K + j
    int j = rem % K, c = rem / K;
    int co  = c * 16 + (lane & 15);
    int cib = kb * 32 + 8 * ((lane >> 4) & 3);
    short8 v;
    #pragma unroll
    for (int i = 0; i < 8; ++i)
        v[i] = bf16r(w2[(co * 64 + (cib + i)) * K + j]);
    *reinterpret_cast<short8*>(wpack + (size_t)u * 8) = v;
}

__global__ __launch_bounds__(256) void pack_kernel(
    const float* __restrict__ w23, const float* __restrict__ w25,
    const float* __restrict__ w27,
    short* __restrict__ wp3, short* __restrict__ wp5, short* __restrict__ wp7)
{
    int tid = blockIdx.x * 256 + threadIdx.x;
    const int n3 = 8 * 3 * 2 * 64;   // 3072
    const int n5 = 8 * 5 * 2 * 64;   // 5120
    const int n7 = 8 * 7 * 2 * 64;   // 7168
    if (tid < n3)                pack_branch<3>(w23, wp3, tid);
    else if (tid < n3 + n5)      pack_branch<5>(w25, wp5, tid - n3);
    else if (tid < n3 + n5 + n7) pack_branch<7>(w27, wp7, tid - n3 - n5);
}

// ---------------------------------------------------------------------------
// branch_mfma<K>: per (bn) block:
//   conv1 (fp32 VALU) -> t1T[l][ci] bf16 in LDS (XOR-swizzled rows)
//   conv2 = MFMA 16x16x32 bf16: A = t1 windows (M=l,K=ci), B = packed w2,
//           tap j shifts the A rows into the SAME accumulator
//   epilogue: +bias, relu, 20-wide pool accumulated via LDS f32 atomics
//   fused xfc partial: xfeatAcc[bn][o] += 0.05 * sum(pooled * w_xfc_slice)
// ---------------------------------------------------------------------------
template<int K>
__global__ __launch_bounds__(256) void branch_mfma(
    const float* __restrict__ x,      // (512, 200)
    const float* __restrict__ xmask,  // (512,)
    const float* __restrict__ w1,     // (64, K)
    const float* __restrict__ b1,     // (64,)
    const float* __restrict__ b2,     // (128,)
    const short* __restrict__ wpack,  // packed bf16 B
    const float* __restrict__ w_xfc,  // (32, 3840)
    float* __restrict__ xfeatAcc,     // (512, 32) f32 accumulator
    int br)
{
    constexpr int PAD = (K - 1) / 2;
    const int bn   = blockIdx.x;
    const int t    = threadIdx.x;
    const int lane = t & 63;
    const int w    = t >> 6;
    const int lane15 = lane & 15;
    const int g      = (lane >> 4) & 3;

    if (xmask[bn] == 0.0f) return;   // contributes exact zeros downstream

    __shared__ float xs[208];
    __shared__ short t1s[232 * 64];      // [row = l+3][ci], XOR-swizzled within row
    __shared__ float pooled_s[128 * 12]; // [co][bin], pad 12
    __shared__ float b2s[128];

    // ---- P0: zero halos / pooled, preload b2 ----
    if (t < 208) xs[t] = 0.0f;
    for (int idx = t; idx < 32 * 64; idx += 256) {   // rows 0..2 and 203..231
        int rr = idx >> 6;
        int row = (rr < 3) ? rr : (200 + rr);
        t1s[row * 64 + (idx & 63)] = 0;
    }
    for (int idx = t; idx < 128 * 12; idx += 256) pooled_s[idx] = 0.0f;
    if (t < 128) b2s[t] = b2[t];
    __syncthreads();

    // ---- P1: load x row ----
    if (t < 200) xs[3 + t] = x[bn * 200 + t];
    __syncthreads();

    // ---- P2: conv1 (thread: fixed ci = lane, l = w + 4k), bf16 transpose-write ----
    {
        const int ci = lane;
        float w1r[K];
        #pragma unroll
        for (int j = 0; j < K; ++j) w1r[j] = w1[ci * K + j];
        const float b1r = b1[ci];
        for (int l = w; l < 200; l += 4) {
            float a = b1r;
            #pragma unroll
            for (int j = 0; j < K; ++j)
                a = fmaf(w1r[j], xs[3 + l + j - PAD], a);
            const int row = l + 3;
            t1s[row * 64 + (ci ^ ((row & 7) << 3))] = bf16r(fmaxf(a, 0.0f));
        }
    }
    __syncthreads();

    // ---- P3: MFMA stage. Wave handles l-tile pairs pp -> (lt0=2pp, lt1=2pp+1). ----
    for (int pp = w; pp < 7; pp += 4) {
        const int lt0 = 2 * pp, lt1 = 2 * pp + 1;
        short8 a0[2 * K], a1[2 * K];
        #pragma unroll
        for (int j = 0; j < K; ++j) {
            const int r0 = lt0 * 16 + lane15 + 3 + j - PAD;
            const int r1 = r0 + 16;
            const int s0 = (r0 & 7) << 3, s1 = (r1 & 7) << 3;
            #pragma unroll
            for (int kb = 0; kb < 2; ++kb) {
                a0[j * 2 + kb] = *reinterpret_cast<const short8*>(
                    &t1s[r0 * 64 + ((kb * 32 + 8 * g) ^ s0)]);
                a1[j * 2 + kb] = *reinterpret_cast<const short8*>(
                    &t1s[r1 * 64 + ((kb * 32 + 8 * g) ^ s1)]);
            }
        }
        for (int c = 0; c < 8; ++c) {
            f32x4 acc0 = {0.f, 0.f, 0.f, 0.f};
            f32x4 acc1 = {0.f, 0.f, 0.f, 0.f};
            const short8* wp = reinterpret_cast<const short8*>(wpack)
                               + (size_t)(c * K * 2) * 64 + lane;
            #pragma unroll
            for (int j = 0; j < K; ++j) {
                #pragma unroll
                for (int kb = 0; kb < 2; ++kb) {
                    short8 bfr = wp[(j * 2 + kb) * 64];
                    acc0 = __builtin_amdgcn_mfma_f32_16x16x32_bf16(
                        a0[j * 2 + kb], bfr, acc0, 0, 0, 0);
                    acc1 = __builtin_amdgcn_mfma_f32_16x16x32_bf16(
                        a1[j * 2 + kb], bfr, acc1, 0, 0, 0);
                }
            }
            // epilogue: bias + relu + pooled atomics (C/D: col=lane&15, row=4g+r)
            const int co = c * 16 + lane15;
            const float bb = b2s[co];
            #pragma unroll
            for (int r = 0; r < 4; ++r) {
                int l = lt0 * 16 + 4 * g + r;
                float v = fmaxf(acc0[r] + bb, 0.0f);
                if (l < 200) atomicAdd(&pooled_s[co * 12 + l / 20], v);
            }
            #pragma unroll
            for (int r = 0; r < 4; ++r) {
                int l = lt1 * 16 + 4 * g + r;
                float v = fmaxf(acc1[r] + bb, 0.0f);
                if (l < 200) atomicAdd(&pooled_s[co * 12 + l / 20], v);
            }
        }
    }
    __syncthreads();

    // ---- P4: fused xfc partial: 8 threads per output o ----
    {
        const int o = t >> 3, part = t & 7;
        const float* wr = w_xfc + o * 3840 + br * 1280;
        float a = 0.0f;
        const int cb = part * 16;
        for (int co = cb; co < cb + 16; ++co) {
            #pragma unroll
            for (int bin = 0; bin < 10; ++bin)
                a = fmaf(pooled_s[co * 12 + bin], wr[co * 10 + bin], a);
        }
        a += __shfl_xor(a, 1);
        a += __shfl_xor(a, 2);
        a += __shfl_xor(a, 4);
        if (part == 0) atomicAdd(&xfeatAcc[bn * 32 + o], a * 0.05f);
    }
}

// ---------------------------------------------------------------------------
// Tail: elements processor + fuse + 4-head attention + pool + regressor.
// One block per batch b (32 blocks). xfeat = (xfeatAcc + b_xfc) * xmask.
// ---------------------------------------------------------------------------
__global__ __launch_bounds__(256) void tail_kernel(
    const float* __restrict__ xfeatAcc,   // (512, 32)
    const float* __restrict__ b_xfc,      // (32,)
    const float* __restrict__ xmaskp,     // (512,)
    const float* __restrict__ elem_info,  // (32, 16, 7)
    const float* __restrict__ emaskp,     // (32, 16)
    const float* __restrict__ w_float, const float* __restrict__ b_float,
    const float* __restrict__ atom_emb, const float* __restrict__ type_emb,
    const float* __restrict__ w_fuse,  const float* __restrict__ b_fuse,
    const float* __restrict__ in_w,    const float* __restrict__ in_b,
    const float* __restrict__ out_w,   const float* __restrict__ out_b,
    const float* __restrict__ w_fc1,   const float* __restrict__ b_fc1,
    const float* __restrict__ w_fc2,   const float* __restrict__ b_fc2,
    float* __restrict__ out)              // (32,)
{
    const int b = blockIdx.x;
    const int t = threadIdx.x;

    __shared__ float fu[16][60];
    __shared__ float fused[16][64];
    __shared__ float qkvs[16][192];
    __shared__ float sc[4][16][16];
    __shared__ float ao[16][64];
    __shared__ float aoo[16][64];
    __shared__ float p2s[64];
    __shared__ float hs[64];
    __shared__ float em[16];

    if (t < 16) em[t] = emaskp[b * 16 + t];
    for (int d = t; d < 512; d += 256) {
        int n = d >> 5, o = d & 31;
        fu[n][o] = (xfeatAcc[(b * 16 + n) * 32 + o] + b_xfc[o]) * xmaskp[b * 16 + n];
    }
    __syncthreads();

    {
        int n = t >> 4, slot = t & 15;
        float m  = em[n];
        float vE = (m >= 0.5f) ? 1.0f : 0.0f;
        const float* ei = elem_info + (b * 16 + n) * 7;
        float a = b_float[slot];
        #pragma unroll
        for (int i = 0; i < 5; ++i)
            a = fmaf(ei[i] * m, w_float[slot * 5 + i], a);
        fu[n][32 + slot] = fmaxf(a, 0.0f) * vE * m;

        int an = (int)(ei[5] * m);
        int et = (int)(ei[6] * m);
        float take = (vE != 0.0f && an >= 1 && an <= 94) ? 1.0f : 0.0f;
        int anc = an < 0 ? 0 : (an > 94 ? 94 : an);
        int etc = et < 0 ? 0 : (et > 5 ? 5 : et);
        if (slot < 8)
            fu[n][48 + slot] = atom_emb[anc * 8 + slot] * take * m;
        else if (slot < 12)
            fu[n][56 + (slot - 8)] = type_emb[etc * 4 + (slot - 8)] * take * m;
    }
    __syncthreads();

    for (int d = t; d < 1024; d += 256) {
        int n = d >> 6, o = d & 63;
        float a = b_fuse[o];
        const float* wr = w_fuse + o * 60;
        #pragma unroll
        for (int i = 0; i < 60; ++i) a = fmaf(fu[n][i], wr[i], a);
        fused[n][o] = a * em[n];
    }
    __syncthreads();

    for (int d = t; d < 3072; d += 256) {
        int n = d / 192, rr = d - n * 192;
        float a = in_b[rr];
        const float* wr = in_w + rr * 64;
        #pragma unroll
        for (int i = 0; i < 64; ++i) a = fmaf(fused[n][i], wr[i], a);
        qkvs[n][rr] = a;
    }
    __syncthreads();

    for (int d = t; d < 1024; d += 256) {
        int h = d >> 8, i = (d >> 4) & 15, j = d & 15;
        float a = 0.0f;
        #pragma unroll
        for (int dd = 0; dd < 16; ++dd)
            a = fmaf(qkvs[i][h * 16 + dd], qkvs[j][64 + h * 16 + dd], a);
        a *= 0.25f;
        if (em[j] < 0.5f) a = -1e30f;
        sc[h][i][j] = a;
    }
    __syncthreads();

    if (t < 64) {
        int h = t >> 4, i = t & 15;
        float mx = -3.4e38f;
        #pragma unroll
        for (int j = 0; j < 16; ++j) mx = fmaxf(mx, sc[h][i][j]);
        float e[16];
        float s = 0.0f;
        #pragma unroll
        for (int j = 0; j < 16; ++j) { e[j] = expf(sc[h][i][j] - mx); s += e[j]; }
        float inv = 1.0f / s;
        #pragma unroll
        for (int j = 0; j < 16; ++j) sc[h][i][j] = e[j] * inv;
    }
    __syncthreads();

    for (int d = t; d < 1024; d += 256) {
        int n = d >> 6, e = d & 63, h = e >> 4;
        float a = 0.0f;
        #pragma unroll
        for (int j = 0; j < 16; ++j)
            a = fmaf(sc[h][n][j], qkvs[j][128 + e], a);
        ao[n][e] = a;
    }
    __syncthreads();

    for (int d = t; d < 1024; d += 256) {
        int n = d >> 6, o = d & 63;
        float a = out_b[o];
        const float* wr = out_w + o * 64;
        #pragma unroll
        for (int i = 0; i < 64; ++i) a = fmaf(ao[n][i], wr[i], a);
        aoo[n][o] = a * em[n];
    }
    __syncthreads();

    if (t < 64) {
        float s = 0.0f, ms = 0.0f;
        #pragma unroll
        for (int n = 0; n < 16; ++n) { s += aoo[n][t]; ms += em[n]; }
        p2s[t] = s / (ms + 1e-8f);
    }
    __syncthreads();

    if (t < 64) {
        float a = b_fc1[t];
        const float* wr = w_fc1 + t * 64;
        #pragma unroll
        for (int i = 0; i < 64; ++i) a = fmaf(p2s[i], wr[i], a);
        hs[t] = fmaxf(a, 0.0f);
    }
    __syncthreads();

    if (t < 64) {
        float v = hs[t] * w_fc2[t];
        #pragma unroll
        for (int d2 = 32; d2 >= 1; d2 >>= 1) v += __shfl_xor(v, d2);
        if (t == 0) out[b] = v + b_fc2[0];
    }
}

extern "C" void kernel_launch(void* const* d_in, const int* in_sizes, int n_in,
                              void* d_out, int out_size, void* d_ws, size_t ws_size,
                              hipStream_t stream)
{
    (void)in_sizes; (void)n_in; (void)out_size; (void)ws_size;
    const float* x     = (const float*)d_in[0];
    const float* xmask = (const float*)d_in[1];
    const float* einfo = (const float*)d_in[2];
    const float* emask = (const float*)d_in[3];

    float* xfeatAcc = (float*)d_ws;                       // 512*32 f32 = 64KB
    short* wp3 = (short*)((char*)d_ws + 65536);           // 3072*8 shorts
    short* wp5 = wp3 + 24576;                             // 5120*8 shorts
    short* wp7 = wp5 + 40960;                             // 7168*8 shorts

    hipMemsetAsync(d_ws, 0, 65536, stream);

    pack_kernel<<<60, 256, 0, stream>>>(
        (const float*)d_in[6], (const float*)d_in[10], (const float*)d_in[14],
        wp3, wp5, wp7);

    branch_mfma<3><<<512, 256, 0, stream>>>(x, xmask,
        (const float*)d_in[4],  (const float*)d_in[5],  (const float*)d_in[7],
        wp3, (const float*)d_in[16], xfeatAcc, 0);
    branch_mfma<5><<<512, 256, 0, stream>>>(x, xmask,
        (const float*)d_in[8],  (const float*)d_in[9],  (const float*)d_in[11],
        wp5, (const float*)d_in[16], xfeatAcc, 1);
    branch_mfma<7><<<512, 256, 0, stream>>>(x, xmask,
        (const float*)d_in[12], (const float*)d_in[13], (const float*)d_in[15],
        wp7, (const float*)d_in[16], xfeatAcc, 2);

    tail_kernel<<<32, 256, 0, stream>>>(xfeatAcc,
        (const float*)d_in[17], xmask, einfo, emask,
        (const float*)d_in[18], (const float*)d_in[19],
        (const float*)d_in[20], (const float*)d_in[21],
        (const float*)d_in[22], (const float*)d_in[23],
        (const float*)d_in[24], (const float*)d_in[25],
        (const float*)d_in[26], (const float*)d_in[27],
        (const float*)d_in[28], (const float*)d_in[29],
        (const float*)d_in[30], (const float*)d_in[31],
        (float*)d_out);
}

// Round 3
// 290.936 us; speedup vs baseline: 1.3657x; 1.1413x over previous
//
#include <hip/hip_runtime.h>
#include <math.h>

typedef float f32x4 __attribute__((ext_vector_type(4)));
typedef short short8 __attribute__((ext_vector_type(8)));

__device__ __forceinline__ short bf16r(float f) {
    union { float f; unsigned u; } x; x.f = f;
    unsigned u = x.u + 0x7fffu + ((x.u >> 16) & 1u);
    return (short)(u >> 16);
}

// ---------------------------------------------------------------------------
// pack_kernel: repack w2 (co,ci,j) fp32 -> B-fragment-ordered bf16 so that an
// MFMA B-frag (16x16x32: lane holds B[8*(lane>>4)+i][lane&15]) is one
// coalesced 16B/lane load: wpack[(((c*K+j)*2+kb)*64+lane)*8 + i]
//   element = w2[co = c*16+(lane&15)][ci = kb*32+8*((lane>>4)&3)+i][j]
// ---------------------------------------------------------------------------
template<int K>
__device__ __forceinline__ void pack_branch(const float* __restrict__ w2,
                                            short* __restrict__ wpack, int u) {
    int lane = u & 63;
    int kb   = (u >> 6) & 1;
    int rem  = u >> 7;          // c*K + j
    int j = rem % K, c = rem / K;
    int co  = c * 16 + (lane & 15);
    int cib = kb * 32 + 8 * ((lane >> 4) & 3);
    short8 v;
    #pragma unroll
    for (int i = 0; i < 8; ++i)
        v[i] = bf16r(w2[(co * 64 + (cib + i)) * K + j]);
    *reinterpret_cast<short8*>(wpack + (size_t)u * 8) = v;
}

__global__ __launch_bounds__(256) void pack_kernel(
    const float* __restrict__ w23, const float* __restrict__ w25,
    const float* __restrict__ w27,
    short* __restrict__ wp3, short* __restrict__ wp5, short* __restrict__ wp7)
{
    int tid = blockIdx.x * 256 + threadIdx.x;
    const int n3 = 8 * 3 * 2 * 64;   // 3072
    const int n5 = 8 * 5 * 2 * 64;   // 5120
    const int n7 = 8 * 7 * 2 * 64;   // 7168
    if (tid < n3)                pack_branch<3>(w23, wp3, tid);
    else if (tid < n3 + n5)      pack_branch<5>(w25, wp5, tid - n3);
    else if (tid < n3 + n5 + n7) pack_branch<7>(w27, wp7, tid - n3 - n5);
}

// ---------------------------------------------------------------------------
// branch_body<K>: one (bn, branch) block.
//   conv1 (fp32 VALU) -> t1s[l+3][ci] bf16, XOR-swizzled rows
//   conv2: MFMA 16x16x32 bf16. Waves c-split (wave w owns c = 2w, 2w+1).
//     Per c: B frags (2K) held in registers (one coalesced L2 load each);
//     A frags streamed from LDS per l-tile; tap j = shifted A rows into the
//     SAME accumulator. Live regs ~ B(2K*4) + acc(4) + transients -> no spill.
//   epilogue: bias+relu+20-pool via LDS atomics; fused xfc partial -> global.
// ---------------------------------------------------------------------------
template<int K>
__device__ __forceinline__ void branch_body(
    const int bn, const int t,
    const float* __restrict__ x, const float* __restrict__ xmask,
    const float* __restrict__ w1, const float* __restrict__ b1,
    const float* __restrict__ b2, const short* __restrict__ wpack,
    const float* __restrict__ w_xfc, float* __restrict__ xfeatAcc, int br,
    float* xs, short* t1s, float* pooled_s, float* b2s)
{
    constexpr int PAD = (K - 1) / 2;
    const int lane = t & 63;
    const int w    = t >> 6;
    const int lane15 = lane & 15;
    const int g      = (lane >> 4) & 3;

    if (xmask[bn] == 0.0f) return;   // exact zeros downstream

    // ---- P0: zero halos / pooled, preload b2 ----
    if (t < 208) xs[t] = 0.0f;
    for (int idx = t; idx < 32 * 64; idx += 256) {   // rows 0..2 and 203..231
        int rr = idx >> 6;
        int row = (rr < 3) ? rr : (200 + rr);
        t1s[row * 64 + (idx & 63)] = 0;
    }
    for (int idx = t; idx < 128 * 12; idx += 256) pooled_s[idx] = 0.0f;
    if (t < 128) b2s[t] = b2[t];
    __syncthreads();

    if (t < 200) xs[3 + t] = x[bn * 200 + t];
    __syncthreads();

    // ---- P2: conv1 (ci = lane, l strided by wave), bf16 swizzled write ----
    {
        const int ci = lane;
        float w1r[K];
        #pragma unroll
        for (int j = 0; j < K; ++j) w1r[j] = w1[ci * K + j];
        const float b1r = b1[ci];
        for (int l = w; l < 200; l += 4) {
            float a = b1r;
            #pragma unroll
            for (int j = 0; j < K; ++j)
                a = fmaf(w1r[j], xs[3 + l + j - PAD], a);
            const int row = l + 3;
            t1s[row * 64 + (ci ^ ((row & 7) << 3))] = bf16r(fmaxf(a, 0.0f));
        }
    }
    __syncthreads();

    // ---- P3: MFMA, wave owns c = 2w, 2w+1; B register-stationary per c ----
    const int c0 = 2 * w;
    #pragma unroll
    for (int cc = 0; cc < 2; ++cc) {
        const int c = c0 + cc;
        short8 bfr[2 * K];
        const short8* wp = reinterpret_cast<const short8*>(wpack)
                           + (size_t)(c * K * 2) * 64 + lane;
        #pragma unroll
        for (int f = 0; f < 2 * K; ++f) bfr[f] = wp[f * 64];
        const int co = c * 16 + lane15;
        const float bb = b2s[co];

        for (int lt = 0; lt < 13; ++lt) {
            f32x4 acc = {0.f, 0.f, 0.f, 0.f};
            #pragma unroll
            for (int j = 0; j < K; ++j) {
                const int r = lt * 16 + lane15 + 3 + j - PAD;
                const int s = (r & 7) << 3;
                const int base = r * 64;
                acc = __builtin_amdgcn_mfma_f32_16x16x32_bf16(
                    *reinterpret_cast<const short8*>(&t1s[base + ((8 * g) ^ s)]),
                    bfr[j * 2 + 0], acc, 0, 0, 0);
                acc = __builtin_amdgcn_mfma_f32_16x16x32_bf16(
                    *reinterpret_cast<const short8*>(&t1s[base + ((32 + 8 * g) ^ s)]),
                    bfr[j * 2 + 1], acc, 0, 0, 0);
            }
            // C/D layout: col = lane&15 (co), row = 4g + r4 (l within tile)
            #pragma unroll
            for (int r4 = 0; r4 < 4; ++r4) {
                int l = lt * 16 + 4 * g + r4;
                float v = fmaxf(acc[r4] + bb, 0.0f);
                if (l < 200) atomicAdd(&pooled_s[co * 12 + l / 20], v);
            }
        }
    }
    __syncthreads();

    // ---- P4: fused xfc partial: 8 threads per output o ----
    {
        const int o = t >> 3, part = t & 7;
        const float* wr = w_xfc + o * 3840 + br * 1280;
        float a = 0.0f;
        const int cb = part * 16;
        for (int co2 = cb; co2 < cb + 16; ++co2) {
            #pragma unroll
            for (int bin = 0; bin < 10; ++bin)
                a = fmaf(pooled_s[co2 * 12 + bin], wr[co2 * 10 + bin], a);
        }
        a += __shfl_xor(a, 1);
        a += __shfl_xor(a, 2);
        a += __shfl_xor(a, 4);
        if (part == 0) atomicAdd(&xfeatAcc[bn * 32 + o], a * 0.05f);
    }
}

__global__ __launch_bounds__(256, 3) void branch_fused(
    const float* __restrict__ x, const float* __restrict__ xmask,
    const float* __restrict__ w1_3, const float* __restrict__ b1_3,
    const float* __restrict__ b2_3, const short* __restrict__ wp3,
    const float* __restrict__ w1_5, const float* __restrict__ b1_5,
    const float* __restrict__ b2_5, const short* __restrict__ wp5,
    const float* __restrict__ w1_7, const float* __restrict__ b1_7,
    const float* __restrict__ b2_7, const short* __restrict__ wp7,
    const float* __restrict__ w_xfc, float* __restrict__ xfeatAcc)
{
    __shared__ float xs[208];
    __shared__ short t1s[232 * 64];
    __shared__ float pooled_s[128 * 12];
    __shared__ float b2s[128];

    const int bn = blockIdx.x;
    const int br = blockIdx.y;
    const int t  = threadIdx.x;

    if (br == 0)
        branch_body<3>(bn, t, x, xmask, w1_3, b1_3, b2_3, wp3, w_xfc, xfeatAcc, 0,
                       xs, t1s, pooled_s, b2s);
    else if (br == 1)
        branch_body<5>(bn, t, x, xmask, w1_5, b1_5, b2_5, wp5, w_xfc, xfeatAcc, 1,
                       xs, t1s, pooled_s, b2s);
    else
        branch_body<7>(bn, t, x, xmask, w1_7, b1_7, b2_7, wp7, w_xfc, xfeatAcc, 2,
                       xs, t1s, pooled_s, b2s);
}

// ---------------------------------------------------------------------------
// Tail: elements processor + fuse + 4-head attention + pool + regressor.
// One block per batch b (32 blocks). xfeat = (xfeatAcc + b_xfc) * xmask.
// ---------------------------------------------------------------------------
__global__ __launch_bounds__(256) void tail_kernel(
    const float* __restrict__ xfeatAcc,   // (512, 32)
    const float* __restrict__ b_xfc,      // (32,)
    const float* __restrict__ xmaskp,     // (512,)
    const float* __restrict__ elem_info,  // (32, 16, 7)
    const float* __restrict__ emaskp,     // (32, 16)
    const float* __restrict__ w_float, const float* __restrict__ b_float,
    const float* __restrict__ atom_emb, const float* __restrict__ type_emb,
    const float* __restrict__ w_fuse,  const float* __restrict__ b_fuse,
    const float* __restrict__ in_w,    const float* __restrict__ in_b,
    const float* __restrict__ out_w,   const float* __restrict__ out_b,
    const float* __restrict__ w_fc1,   const float* __restrict__ b_fc1,
    const float* __restrict__ w_fc2,   const float* __restrict__ b_fc2,
    float* __restrict__ out)              // (32,)
{
    const int b = blockIdx.x;
    const int t = threadIdx.x;

    __shared__ float fu[16][60];
    __shared__ float fused[16][64];
    __shared__ float qkvs[16][192];
    __shared__ float sc[4][16][16];
    __shared__ float ao[16][64];
    __shared__ float aoo[16][64];
    __shared__ float p2s[64];
    __shared__ float hs[64];
    __shared__ float em[16];

    if (t < 16) em[t] = emaskp[b * 16 + t];
    for (int d = t; d < 512; d += 256) {
        int n = d >> 5, o = d & 31;
        fu[n][o] = (xfeatAcc[(b * 16 + n) * 32 + o] + b_xfc[o]) * xmaskp[b * 16 + n];
    }
    __syncthreads();

    {
        int n = t >> 4, slot = t & 15;
        float m  = em[n];
        float vE = (m >= 0.5f) ? 1.0f : 0.0f;
        const float* ei = elem_info + (b * 16 + n) * 7;
        float a = b_float[slot];
        #pragma unroll
        for (int i = 0; i < 5; ++i)
            a = fmaf(ei[i] * m, w_float[slot * 5 + i], a);
        fu[n][32 + slot] = fmaxf(a, 0.0f) * vE * m;

        int an = (int)(ei[5] * m);
        int et = (int)(ei[6] * m);
        float take = (vE != 0.0f && an >= 1 && an <= 94) ? 1.0f : 0.0f;
        int anc = an < 0 ? 0 : (an > 94 ? 94 : an);
        int etc = et < 0 ? 0 : (et > 5 ? 5 : et);
        if (slot < 8)
            fu[n][48 + slot] = atom_emb[anc * 8 + slot] * take * m;
        else if (slot < 12)
            fu[n][56 + (slot - 8)] = type_emb[etc * 4 + (slot - 8)] * take * m;
    }
    __syncthreads();

    for (int d = t; d < 1024; d += 256) {
        int n = d >> 6, o = d & 63;
        float a = b_fuse[o];
        const float* wr = w_fuse + o * 60;
        #pragma unroll
        for (int i = 0; i < 60; ++i) a = fmaf(fu[n][i], wr[i], a);
        fused[n][o] = a * em[n];
    }
    __syncthreads();

    for (int d = t; d < 3072; d += 256) {
        int n = d / 192, rr = d - n * 192;
        float a = in_b[rr];
        const float* wr = in_w + rr * 64;
        #pragma unroll
        for (int i = 0; i < 64; ++i) a = fmaf(fused[n][i], wr[i], a);
        qkvs[n][rr] = a;
    }
    __syncthreads();

    for (int d = t; d < 1024; d += 256) {
        int h = d >> 8, i = (d >> 4) & 15, j = d & 15;
        float a = 0.0f;
        #pragma unroll
        for (int dd = 0; dd < 16; ++dd)
            a = fmaf(qkvs[i][h * 16 + dd], qkvs[j][64 + h * 16 + dd], a);
        a *= 0.25f;
        if (em[j] < 0.5f) a = -1e30f;
        sc[h][i][j] = a;
    }
    __syncthreads();

    if (t < 64) {
        int h = t >> 4, i = t & 15;
        float mx = -3.4e38f;
        #pragma unroll
        for (int j = 0; j < 16; ++j) mx = fmaxf(mx, sc[h][i][j]);
        float e[16];
        float s = 0.0f;
        #pragma unroll
        for (int j = 0; j < 16; ++j) { e[j] = expf(sc[h][i][j] - mx); s += e[j]; }
        float inv = 1.0f / s;
        #pragma unroll
        for (int j = 0; j < 16; ++j) sc[h][i][j] = e[j] * inv;
    }
    __syncthreads();

    for (int d = t; d < 1024; d += 256) {
        int n = d >> 6, e = d & 63, h = e >> 4;
        float a = 0.0f;
        #pragma unroll
        for (int j = 0; j < 16; ++j)
            a = fmaf(sc[h][n][j], qkvs[j][128 + e], a);
        ao[n][e] = a;
    }
    __syncthreads();

    for (int d = t; d < 1024; d += 256) {
        int n = d >> 6, o = d & 63;
        float a = out_b[o];
        const float* wr = out_w + o * 64;
        #pragma unroll
        for (int i = 0; i < 64; ++i) a = fmaf(ao[n][i], wr[i], a);
        aoo[n][o] = a * em[n];
    }
    __syncthreads();

    if (t < 64) {
        float s = 0.0f, ms = 0.0f;
        #pragma unroll
        for (int n = 0; n < 16; ++n) { s += aoo[n][t]; ms += em[n]; }
        p2s[t] = s / (ms + 1e-8f);
    }
    __syncthreads();

    if (t < 64) {
        float a = b_fc1[t];
        const float* wr = w_fc1 + t * 64;
        #pragma unroll
        for (int i = 0; i < 64; ++i) a = fmaf(p2s[i], wr[i], a);
        hs[t] = fmaxf(a, 0.0f);
    }
    __syncthreads();

    if (t < 64) {
        float v = hs[t] * w_fc2[t];
        #pragma unroll
        for (int d2 = 32; d2 >= 1; d2 >>= 1) v += __shfl_xor(v, d2);
        if (t == 0) out[b] = v + b_fc2[0];
    }
}

extern "C" void kernel_launch(void* const* d_in, const int* in_sizes, int n_in,
                              void* d_out, int out_size, void* d_ws, size_t ws_size,
                              hipStream_t stream)
{
    (void)in_sizes; (void)n_in; (void)out_size; (void)ws_size;
    const float* x     = (const float*)d_in[0];
    const float* xmask = (const float*)d_in[1];
    const float* einfo = (const float*)d_in[2];
    const float* emask = (const float*)d_in[3];

    float* xfeatAcc = (float*)d_ws;                       // 512*32 f32 = 64KB
    short* wp3 = (short*)((char*)d_ws + 65536);           // 3072*8 shorts
    short* wp5 = wp3 + 24576;                             // 5120*8 shorts
    short* wp7 = wp5 + 40960;                             // 7168*8 shorts

    hipMemsetAsync(d_ws, 0, 65536, stream);

    pack_kernel<<<60, 256, 0, stream>>>(
        (const float*)d_in[6], (const float*)d_in[10], (const float*)d_in[14],
        wp3, wp5, wp7);

    branch_fused<<<dim3(512, 3), 256, 0, stream>>>(x, xmask,
        (const float*)d_in[4],  (const float*)d_in[5],  (const float*)d_in[7],  wp3,
        (const float*)d_in[8],  (const float*)d_in[9],  (const float*)d_in[11], wp5,
        (const float*)d_in[12], (const float*)d_in[13], (const float*)d_in[15], wp7,
        (const float*)d_in[16], xfeatAcc);

    tail_kernel<<<32, 256, 0, stream>>>(xfeatAcc,
        (const float*)d_in[17], xmask, einfo, emask,
        (const float*)d_in[18], (const float*)d_in[19],
        (const float*)d_in[20], (const float*)d_in[21],
        (const float*)d_in[22], (const float*)d_in[23],
        (const float*)d_in[24], (const float*)d_in[25],
        (const float*)d_in[26], (const float*)d_in[27],
        (const float*)d_in[28], (const float*)d_in[29],
        (const float*)d_in[30], (const float*)d_in[31],
        (float*)d_out);
}